// Round 7
// baseline (224.314 us; speedup 1.0000x reference)
//
#include <hip/hip_runtime.h>
#include <hip/hip_bf16.h>
#include <math.h>

// Problem: B=2, N=2048, D_MODEL=1024, H=16, D_HEAD=64. fp32 in/out,
// bf16 MFMA internal (threshold is bf16-grade: 2% of max|ref|).
#define BATCH 2
#define NSEQ  2048
#define DM    1024
#define NH    16
#define DH    64
#define EPS_N 1e-6f

typedef unsigned short u16;
typedef __attribute__((ext_vector_type(8))) short short8;       // bf16x8 MFMA frag
typedef __attribute__((ext_vector_type(8))) unsigned short u16x8;
typedef __attribute__((ext_vector_type(4))) unsigned short u16x4;
typedef __attribute__((ext_vector_type(4))) float f32x4;

__device__ __forceinline__ u16 f2bf(float x) {
  __hip_bfloat16 h = __float2bfloat16(x);          // round-to-nearest-even
  return *reinterpret_cast<u16*>(&h);
}

// async 16B global->LDS (lane i lands at lds_base + 16*i)
__device__ __forceinline__ void gl_lds16(const u16* g, u16* lds_base) {
  __builtin_amdgcn_global_load_lds(
      (__attribute__((address_space(1))) void*)g,
      (__attribute__((address_space(3))) void*)lds_base, 16, 0, 0);
}

// ---------------------------------------------------------------------------
// Prep: blocks 0..1023 transpose+cast the 4 weight matrices (out[n][k] =
// bf16(in[k][n])); blocks 1024..3071 cast X fp32->bf16. grid 3072, 256 thr.
// ---------------------------------------------------------------------------
__global__ __launch_bounds__(256) void prep(
    const float* __restrict__ X,
    const float* __restrict__ w0, const float* __restrict__ w1,
    const float* __restrict__ w2, const float* __restrict__ w3,
    u16* __restrict__ Xb, u16* __restrict__ WT) {
  const int id = blockIdx.x, tid = threadIdx.x;
  if (id >= 1024) {                       // ---- cast X chunk
    size_t base = ((size_t)(id - 1024) * 256 + tid) * 8;
    float4 f0 = *(const float4*)&X[base];
    float4 f1 = *(const float4*)&X[base + 4];
    u16x8 v;
    v[0] = f2bf(f0.x); v[1] = f2bf(f0.y); v[2] = f2bf(f0.z); v[3] = f2bf(f0.w);
    v[4] = f2bf(f1.x); v[5] = f2bf(f1.y); v[6] = f2bf(f1.z); v[7] = f2bf(f1.w);
    *(u16x8*)&Xb[base] = v;
    return;
  }
  // ---- weight transpose tile
  const int z = id >> 8, xy = id & 255, bx = xy & 15, by = xy >> 4;
  const float* in = (z == 0) ? w0 : (z == 1) ? w1 : (z == 2) ? w2 : w3;
  u16* o = WT + (size_t)z * DM * DM;
  __shared__ u16 T[64][65];
  const int n0 = bx * 64, k0 = by * 64;
  #pragma unroll
  for (int i = 0; i < 4; i++) {
    int c = tid + 256 * i, row = c >> 4, col4 = c & 15;
    float4 f = *(const float4*)&in[(size_t)(k0 + row) * DM + n0 + col4 * 4];
    T[row][col4 * 4 + 0] = f2bf(f.x);
    T[row][col4 * 4 + 1] = f2bf(f.y);
    T[row][col4 * 4 + 2] = f2bf(f.z);
    T[row][col4 * 4 + 3] = f2bf(f.w);
  }
  __syncthreads();
  #pragma unroll
  for (int i = 0; i < 2; i++) {
    int c = tid + 256 * i, row = c >> 3, col8 = c & 7;
    u16x8 v;
    #pragma unroll
    for (int e = 0; e < 8; e++) v[e] = T[col8 * 8 + e][row];
    *(u16x8*)&o[(size_t)(n0 + row) * DM + k0 + col8 * 8] = v;
  }
}

// ===========================================================================
// m97-style 128x128 GEMM mainloop (BK=64, global_load_lds 16B, XOR-swizzled
// LDS chunks). A[m][k], Bt[n][k] both bf16. 256 thr, 4 waves in 2x2 (wm,wn).
// LDS: row r (128 B) holds global chunk g at position g^(r&7).
// ===========================================================================
#define GEMM128_MAINLOOP(Aptr, Btptr)                                          \
  __shared__ u16 As[128 * 64];                                                 \
  __shared__ u16 Bs[128 * 64];                                                 \
  const int tid = threadIdx.x, w = tid >> 6, lane = tid & 63;                  \
  const int ml = lane & 15, quad = lane >> 4;                                  \
  const int m0 = blockIdx.y * 128, n0 = blockIdx.x * 128;                      \
  const int wm = w & 1, wn = w >> 1;                                           \
  const int srow = lane >> 3;                 /* 0..7 within 8-row slab */     \
  const int scol = ((lane & 7) ^ srow) * 8;   /* swizzled global chunk */      \
  f32x4 acc[4][4];                                                             \
  _Pragma("unroll") for (int mi = 0; mi < 4; mi++)                             \
    _Pragma("unroll") for (int ni = 0; ni < 4; ni++)                           \
      _Pragma("unroll") for (int e = 0; e < 4; e++) acc[mi][ni][e] = 0.f;      \
  for (int k0 = 0; k0 < DM; k0 += 64) {                                        \
    __syncthreads();                                                           \
    _Pragma("unroll") for (int L = 0; L < 4; L++) {                            \
      int I = w * 4 + L;                                                       \
      gl_lds16(Aptr  + (size_t)(m0 + I * 8 + srow) * DM + k0 + scol,           \
               As + I * 512);                                                  \
      gl_lds16(Btptr + (size_t)(n0 + I * 8 + srow) * DM + k0 + scol,           \
               Bs + I * 512);                                                  \
    }                                                                          \
    __syncthreads();                                                           \
    _Pragma("unroll") for (int kk = 0; kk < 64; kk += 32) {                    \
      const int kc = kk >> 3;                 /* chunk base: 0 or 4 */         \
      short8 am[4], bn[4];                                                     \
      _Pragma("unroll") for (int i = 0; i < 4; i++) {                          \
        int ra = wm * 64 + i * 16 + ml;                                        \
        int rb = wn * 64 + i * 16 + ml;                                        \
        am[i] = *(const short8*)&As[ra * 64 + (((quad + kc) ^ (ra & 7)) * 8)]; \
        bn[i] = *(const short8*)&Bs[rb * 64 + (((quad + kc) ^ (rb & 7)) * 8)]; \
      }                                                                        \
      _Pragma("unroll") for (int mi = 0; mi < 4; mi++)                         \
        _Pragma("unroll") for (int ni = 0; ni < 4; ni++)                       \
          acc[mi][ni] = __builtin_amdgcn_mfma_f32_16x16x32_bf16(               \
              am[mi], bn[ni], acc[mi][ni], 0, 0, 0);                           \
    }                                                                          \
  }

// ---------------------------------------------------------------------------
// QKV GEMM + fused L2 norm: Xb[4096][1024] bf16 @ W. z selects Q/K/V.
// Q,K: per-(head,token) L2-normalized in-register (Q also x1/8), -> [B,H,N,DH].
// V -> transposed [B,H,DH,N] (packed 8B stores). grid (8, 32, 3), 256 thr.
// ---------------------------------------------------------------------------
__global__ __launch_bounds__(256) void gemm_qkv128(
    const u16* __restrict__ Xb, const u16* __restrict__ WT,
    u16* __restrict__ Qo, u16* __restrict__ Ko, u16* __restrict__ Vt) {
  const u16* Bt = WT + (size_t)blockIdx.z * DM * DM;
  GEMM128_MAINLOOP(Xb, Bt)
  const int z = blockIdx.z;
  if (z < 2) {
    u16* OutQK = (z == 0) ? Qo : Ko;
    const float qsc = (z == 0) ? 0.125f : 1.0f;     // fold softmax 1/sqrt(64)
    const int h = (n0 >> 6) + wn;                   // head of this wave's cols
    #pragma unroll
    for (int mi = 0; mi < 4; mi++) {
      int mrow0 = m0 + wm * 64 + mi * 16 + quad * 4;
      int b = mrow0 >> 11, tok0 = mrow0 & (NSEQ - 1);
      #pragma unroll
      for (int r = 0; r < 4; r++) {
        float ss = 0.f;
        #pragma unroll
        for (int ni = 0; ni < 4; ni++) ss += acc[mi][ni][r] * acc[mi][ni][r];
        ss += __shfl_xor(ss, 1, 64);
        ss += __shfl_xor(ss, 2, 64);
        ss += __shfl_xor(ss, 4, 64);
        ss += __shfl_xor(ss, 8, 64);    // sum over the 16 ml lanes (full row)
        float sc = qsc / (sqrtf(ss) + EPS_N);
        #pragma unroll
        for (int ni = 0; ni < 4; ni++)
          OutQK[((size_t)(b * NH + h) * NSEQ + tok0 + r) * DH + ni * 16 + ml] =
              f2bf(acc[mi][ni][r] * sc);
      }
    }
  } else {
    #pragma unroll
    for (int mi = 0; mi < 4; mi++) {
      int mrow0 = m0 + wm * 64 + mi * 16 + quad * 4;
      int b = mrow0 >> 11, tok0 = mrow0 & (NSEQ - 1);
      #pragma unroll
      for (int ni = 0; ni < 4; ni++) {
        int n = n0 + wn * 64 + ni * 16 + ml;
        int h = n >> 6, d = n & 63;
        u16x4 pk;
        #pragma unroll
        for (int r = 0; r < 4; r++) pk[r] = f2bf(acc[mi][ni][r]);
        *(u16x4*)&Vt[((size_t)(b * NH + h) * DH + d) * NSEQ + tok0] = pk;
      }
    }
  }
}

// ---------------------------------------------------------------------------
// Output projection: out = vhat[4096][1024] @ Wo + bo, fp32 out.
// grid (8, 32), 256 thr.
// ---------------------------------------------------------------------------
__global__ __launch_bounds__(256) void gemm_proj128(
    const u16* __restrict__ A, const u16* __restrict__ BtW,
    const float* __restrict__ bias, float* __restrict__ out) {
  GEMM128_MAINLOOP(A, BtW)
  #pragma unroll
  for (int ni = 0; ni < 4; ni++) {
    int n = n0 + wn * 64 + ni * 16 + ml;
    float bz = bias[n];
    #pragma unroll
    for (int mi = 0; mi < 4; mi++) {
      int mrow0 = m0 + wm * 64 + mi * 16 + quad * 4;
      #pragma unroll
      for (int r = 0; r < 4; r++)
        out[(size_t)(mrow0 + r) * DM + n] = acc[mi][ni][r] + bz;
    }
  }
}

// ---------------------------------------------------------------------------
// Barrier-free MFMA flash attention, causal, NO online max (|score|<=0.125 by
// L2 norm -> fixed softmax max=0; O and l are additive).
// One wave per block (64 thr). Wave owns 32 q-rows, loops over 32-key steps.
// K[key][d] and Vt[d][key] give 16B-contiguous B-frags -> read DIRECTLY from
// global (L2-resident: XCD-pinned via bh = blockIdx.x). No __syncthreads at
// all; K-frags pipelined across steps via WAR ordering (fine-grained vmcnt).
// Only LDS: per-wave 32x40 P round-trip (C->A layout transform).
// Heavy q-blocks dispatch first: qblk = 63 - blockIdx.y.
// grid (32, 64), 64 thr.
// ---------------------------------------------------------------------------
__global__ __launch_bounds__(64) void flash_attn(
    const u16* __restrict__ Qb, const u16* __restrict__ Kb,
    const u16* __restrict__ Vt, u16* __restrict__ vhat) {
  const int lane = threadIdx.x;
  const int ml = lane & 15, quad = lane >> 4;
  const int bh = blockIdx.x;                  // 0..31 (= b*NH + h)
  const int bb = bh >> 4, hb = bh & 15;
  const int qblk = 63 - (int)blockIdx.y;      // heavy blocks first
  const int q0 = qblk * 32;
  const int nsteps = qblk + 1;                // 32-key steps
  const u16* Qh = Qb + (size_t)bh * NSEQ * DH;
  const u16* Kh = Kb + (size_t)bh * NSEQ * DH;
  const u16* Vth = Vt + (size_t)bh * DH * NSEQ;

  __shared__ u16 Ps[32][40];   // row 80 B (16B-aligned rows, 2-way-free banks)

  // Q A-frags: A[m=ml][k=quad*8+j]; m-tiles x k-chunks
  short8 aq[2][2];
  #pragma unroll
  for (int m = 0; m < 2; m++)
    #pragma unroll
    for (int c = 0; c < 2; c++)
      aq[m][c] = *(const short8*)
          &Qh[(size_t)(q0 + m * 16 + ml) * DH + c * 32 + quad * 8];

  f32x4 oacc[2][4];
  #pragma unroll
  for (int m = 0; m < 2; m++)
    #pragma unroll
    for (int n = 0; n < 4; n++)
      #pragma unroll
      for (int e = 0; e < 4; e++) oacc[m][n][e] = 0.f;
  float l_[2][4] = {{0.f, 0.f, 0.f, 0.f}, {0.f, 0.f, 0.f, 0.f}};

  // preload K frags for step 0: B-frag = K[key=n*16+ml][d=c*32+quad*8+j]
  short8 kf[2][2];
  #pragma unroll
  for (int n = 0; n < 2; n++)
    #pragma unroll
    for (int c = 0; c < 2; c++)
      kf[n][c] = *(const short8*)
          &Kh[(size_t)(n * 16 + ml) * DH + c * 32 + quad * 8];

  for (int s = 0; s < nsteps; s++) {
    const int j0 = s * 32;
    // V frags for THIS step (latency covered by S-MFMAs + exp):
    // B-frag = V^T[d=n*16+ml][key=quad*8+j]
    short8 vf[4];
    #pragma unroll
    for (int n = 0; n < 4; n++)
      vf[n] = *(const short8*)&Vth[(size_t)(n * 16 + ml) * NSEQ + j0 + quad * 8];

    // S = Q·K^T (32q x 32k) using kf loaded last iteration
    f32x4 sacc[2][2];
    #pragma unroll
    for (int m = 0; m < 2; m++)
      #pragma unroll
      for (int n = 0; n < 2; n++) {
        #pragma unroll
        for (int e = 0; e < 4; e++) sacc[m][n][e] = 0.f;
        #pragma unroll
        for (int c = 0; c < 2; c++)
          sacc[m][n] = __builtin_amdgcn_mfma_f32_16x16x32_bf16(
              aq[m][c], kf[n][c], sacc[m][n], 0, 0, 0);
      }

    // issue K loads for NEXT step (WAR on kf: issues right after S consumes)
    const int j0n = (j0 + 32 < NSEQ) ? (j0 + 32) : (NSEQ - 32);
    #pragma unroll
    for (int n = 0; n < 2; n++)
      #pragma unroll
      for (int c = 0; c < 2; c++)
        kf[n][c] = *(const short8*)
            &Kh[(size_t)(j0n + n * 16 + ml) * DH + c * 32 + quad * 8];

    // p = exp(s), causal mask on last step only. C-layout: col=ml(key),
    // row=quad*4+r(q).
    const bool lastt = (s == nsteps - 1);
    #pragma unroll
    for (int m = 0; m < 2; m++)
      #pragma unroll
      for (int n = 0; n < 2; n++) {
        int j = j0 + n * 16 + ml;
        #pragma unroll
        for (int r = 0; r < 4; r++) {
          int q = q0 + m * 16 + quad * 4 + r;
          float e = __expf(sacc[m][n][r]);
          e = (lastt && j > q) ? 0.f : e;
          l_[m][r] += e;
          Ps[m * 16 + quad * 4 + r][n * 16 + ml] = f2bf(e);
        }
      }

    // O += P·V : A-frag = Ps[q=m*16+ml][key=quad*8+j] (same-wave lgkmcnt
    // ordering, no barrier)
    #pragma unroll
    for (int m = 0; m < 2; m++) {
      short8 ap = *(const short8*)&Ps[m * 16 + ml][quad * 8];
      #pragma unroll
      for (int n = 0; n < 4; n++)
        oacc[m][n] = __builtin_amdgcn_mfma_f32_16x16x32_bf16(
            ap, vf[n], oacc[m][n], 0, 0, 0);
    }
  }

  // epilogue: reduce l over the 16 ml lanes of each quad group, write vhat
  #pragma unroll
  for (int m = 0; m < 2; m++)
    #pragma unroll
    for (int r = 0; r < 4; r++) {
      float lv = l_[m][r];
      lv += __shfl_xor(lv, 1, 64);
      lv += __shfl_xor(lv, 2, 64);
      lv += __shfl_xor(lv, 4, 64);
      lv += __shfl_xor(lv, 8, 64);
      float inv = 1.f / lv;
      int q = q0 + m * 16 + quad * 4 + r;
      #pragma unroll
      for (int n = 0; n < 4; n++)
        vhat[((size_t)(bb * NSEQ + q)) * DM + hb * DH + n * 16 + ml] =
            f2bf(oacc[m][n][r] * inv);
    }
}

// ---------------------------------------------------------------------------
extern "C" void kernel_launch(void* const* d_in, const int* in_sizes, int n_in,
                              void* d_out, int out_size, void* d_ws, size_t ws_size,
                              hipStream_t stream) {
  const float* X  = (const float*)d_in[0];
  const float* Wq = (const float*)d_in[1];
  const float* Wk = (const float*)d_in[2];
  const float* Wv = (const float*)d_in[3];
  const float* Wo = (const float*)d_in[4];
  const float* bo = (const float*)d_in[5];
  float* out = (float*)d_out;

  // ws (all bf16, 8 MB each): Qb | Kb | Vt[B,H,DH,N] | {Xb then vhat, aliased}
  // | WT (4 transposed weights, 8 MB total) = 40 MB
  const size_t NE = (size_t)BATCH * NSEQ * DM;   // 4,194,304
  u16* Qb   = (u16*)d_ws;
  u16* Kb   = Qb + NE;
  u16* Vt   = Kb + NE;
  u16* XbVh = Vt + NE;                           // Xb / vhat (disjoint lifetimes)
  u16* WT   = XbVh + NE;

  prep        <<<dim3(3072),      256, 0, stream>>>(X, Wq, Wk, Wv, Wo, XbVh, WT);
  gemm_qkv128 <<<dim3(8, 32, 3),  256, 0, stream>>>(XbVh, WT, Qb, Kb, Vt);
  flash_attn  <<<dim3(32, 64),     64, 0, stream>>>(Qb, Kb, Vt, XbVh);
  gemm_proj128<<<dim3(8, 32, 1),  256, 0, stream>>>(XbVh, WT + 3 * (size_t)DM * DM,
                                                    bo, out);
}

// Round 9
// 224.209 us; speedup vs baseline: 1.0005x; 1.0005x over previous
//
#include <hip/hip_runtime.h>
#include <hip/hip_bf16.h>
#include <math.h>

// Problem: B=2, N=2048, D_MODEL=1024, H=16, D_HEAD=64. fp32 in/out,
// bf16 MFMA internal (threshold is bf16-grade: 2% of max|ref|).
#define BATCH 2
#define NSEQ  2048
#define DM    1024
#define NH    16
#define DH    64
#define EPS_N 1e-6f

typedef unsigned short u16;
typedef __attribute__((ext_vector_type(8))) short short8;       // bf16x8 MFMA frag
typedef __attribute__((ext_vector_type(8))) unsigned short u16x8;
typedef __attribute__((ext_vector_type(4))) unsigned short u16x4;
typedef __attribute__((ext_vector_type(4))) float f32x4;

__device__ __forceinline__ u16 f2bf(float x) {
  __hip_bfloat16 h = __float2bfloat16(x);          // round-to-nearest-even
  return *reinterpret_cast<u16*>(&h);
}

// async 16B global->LDS (lane i lands at lds_base + 16*i)
__device__ __forceinline__ void gl_lds16(const u16* g, u16* lds_base) {
  __builtin_amdgcn_global_load_lds(
      (__attribute__((address_space(1))) void*)g,
      (__attribute__((address_space(3))) void*)lds_base, 16, 0, 0);
}

// ---------------------------------------------------------------------------
// Prep: blocks 0..1023 transpose+cast the 4 weight matrices (out[n][k] =
// bf16(in[k][n])); blocks 1024..3071 cast X fp32->bf16. grid 3072, 256 thr.
// ---------------------------------------------------------------------------
__global__ __launch_bounds__(256) void prep(
    const float* __restrict__ X,
    const float* __restrict__ w0, const float* __restrict__ w1,
    const float* __restrict__ w2, const float* __restrict__ w3,
    u16* __restrict__ Xb, u16* __restrict__ WT) {
  const int id = blockIdx.x, tid = threadIdx.x;
  if (id >= 1024) {                       // ---- cast X chunk
    size_t base = ((size_t)(id - 1024) * 256 + tid) * 8;
    float4 f0 = *(const float4*)&X[base];
    float4 f1 = *(const float4*)&X[base + 4];
    u16x8 v;
    v[0] = f2bf(f0.x); v[1] = f2bf(f0.y); v[2] = f2bf(f0.z); v[3] = f2bf(f0.w);
    v[4] = f2bf(f1.x); v[5] = f2bf(f1.y); v[6] = f2bf(f1.z); v[7] = f2bf(f1.w);
    *(u16x8*)&Xb[base] = v;
    return;
  }
  // ---- weight transpose tile
  const int z = id >> 8, xy = id & 255, bx = xy & 15, by = xy >> 4;
  const float* in = (z == 0) ? w0 : (z == 1) ? w1 : (z == 2) ? w2 : w3;
  u16* o = WT + (size_t)z * DM * DM;
  __shared__ u16 T[64][65];
  const int n0 = bx * 64, k0 = by * 64;
  #pragma unroll
  for (int i = 0; i < 4; i++) {
    int c = tid + 256 * i, row = c >> 4, col4 = c & 15;
    float4 f = *(const float4*)&in[(size_t)(k0 + row) * DM + n0 + col4 * 4];
    T[row][col4 * 4 + 0] = f2bf(f.x);
    T[row][col4 * 4 + 1] = f2bf(f.y);
    T[row][col4 * 4 + 2] = f2bf(f.z);
    T[row][col4 * 4 + 3] = f2bf(f.w);
  }
  __syncthreads();
  #pragma unroll
  for (int i = 0; i < 2; i++) {
    int c = tid + 256 * i, row = c >> 3, col8 = c & 7;
    u16x8 v;
    #pragma unroll
    for (int e = 0; e < 8; e++) v[e] = T[col8 * 8 + e][row];
    *(u16x8*)&o[(size_t)(n0 + row) * DM + k0 + col8 * 8] = v;
  }
}

// ===========================================================================
// m97-style 128x128 GEMM mainloop (BK=64, global_load_lds 16B, XOR-swizzled
// LDS chunks). A[m][k], Bt[n][k] both bf16. 256 thr, 4 waves in 2x2 (wm,wn).
// LDS: row r (128 B) holds global chunk g at position g^(r&7).
// ===========================================================================
#define GEMM128_MAINLOOP(Aptr, Btptr)                                          \
  __shared__ u16 As[128 * 64];                                                 \
  __shared__ u16 Bs[128 * 64];                                                 \
  const int tid = threadIdx.x, w = tid >> 6, lane = tid & 63;                  \
  const int ml = lane & 15, quad = lane >> 4;                                  \
  const int m0 = blockIdx.y * 128, n0 = blockIdx.x * 128;                      \
  const int wm = w & 1, wn = w >> 1;                                           \
  const int srow = lane >> 3;                 /* 0..7 within 8-row slab */     \
  const int scol = ((lane & 7) ^ srow) * 8;   /* swizzled global chunk */      \
  f32x4 acc[4][4];                                                             \
  _Pragma("unroll") for (int mi = 0; mi < 4; mi++)                             \
    _Pragma("unroll") for (int ni = 0; ni < 4; ni++)                           \
      _Pragma("unroll") for (int e = 0; e < 4; e++) acc[mi][ni][e] = 0.f;      \
  for (int k0 = 0; k0 < DM; k0 += 64) {                                        \
    __syncthreads();                                                           \
    _Pragma("unroll") for (int L = 0; L < 4; L++) {                            \
      int I = w * 4 + L;                                                       \
      gl_lds16(Aptr  + (size_t)(m0 + I * 8 + srow) * DM + k0 + scol,           \
               As + I * 512);                                                  \
      gl_lds16(Btptr + (size_t)(n0 + I * 8 + srow) * DM + k0 + scol,           \
               Bs + I * 512);                                                  \
    }                                                                          \
    __syncthreads();                                                           \
    _Pragma("unroll") for (int kk = 0; kk < 64; kk += 32) {                    \
      const int kc = kk >> 3;                 /* chunk base: 0 or 4 */         \
      short8 am[4], bn[4];                                                     \
      _Pragma("unroll") for (int i = 0; i < 4; i++) {                          \
        int ra = wm * 64 + i * 16 + ml;                                        \
        int rb = wn * 64 + i * 16 + ml;                                        \
        am[i] = *(const short8*)&As[ra * 64 + (((quad + kc) ^ (ra & 7)) * 8)]; \
        bn[i] = *(const short8*)&Bs[rb * 64 + (((quad + kc) ^ (rb & 7)) * 8)]; \
      }                                                                        \
      _Pragma("unroll") for (int mi = 0; mi < 4; mi++)                         \
        _Pragma("unroll") for (int ni = 0; ni < 4; ni++)                       \
          acc[mi][ni] = __builtin_amdgcn_mfma_f32_16x16x32_bf16(               \
              am[mi], bn[ni], acc[mi][ni], 0, 0, 0);                           \
    }                                                                          \
  }

// ---------------------------------------------------------------------------
// QKV GEMM + fused L2 norm: Xb[4096][1024] bf16 @ W. z selects Q/K/V.
// Q,K: per-(head,token) L2-normalized in-register; Q also gets
// 0.125*log2(e) folded in (softmax 1/sqrt(64) + exp->exp2 conversion).
// V -> transposed [B,H,DH,N] (packed 8B stores). grid (8, 32, 3), 256 thr.
// ---------------------------------------------------------------------------
__global__ __launch_bounds__(256) void gemm_qkv128(
    const u16* __restrict__ Xb, const u16* __restrict__ WT,
    u16* __restrict__ Qo, u16* __restrict__ Ko, u16* __restrict__ Vt) {
  const u16* Bt = WT + (size_t)blockIdx.z * DM * DM;
  GEMM128_MAINLOOP(Xb, Bt)
  const int z = blockIdx.z;
  if (z < 2) {
    u16* OutQK = (z == 0) ? Qo : Ko;
    const float qsc = (z == 0) ? 0.125f * 1.44269504f : 1.0f;
    const int h = (n0 >> 6) + wn;                   // head of this wave's cols
    #pragma unroll
    for (int mi = 0; mi < 4; mi++) {
      int mrow0 = m0 + wm * 64 + mi * 16 + quad * 4;
      int b = mrow0 >> 11, tok0 = mrow0 & (NSEQ - 1);
      #pragma unroll
      for (int r = 0; r < 4; r++) {
        float ss = 0.f;
        #pragma unroll
        for (int ni = 0; ni < 4; ni++) ss += acc[mi][ni][r] * acc[mi][ni][r];
        ss += __shfl_xor(ss, 1, 64);
        ss += __shfl_xor(ss, 2, 64);
        ss += __shfl_xor(ss, 4, 64);
        ss += __shfl_xor(ss, 8, 64);    // sum over the 16 ml lanes (full row)
        float sc = qsc / (sqrtf(ss) + EPS_N);
        #pragma unroll
        for (int ni = 0; ni < 4; ni++)
          OutQK[((size_t)(b * NH + h) * NSEQ + tok0 + r) * DH + ni * 16 + ml] =
              f2bf(acc[mi][ni][r] * sc);
      }
    }
  } else {
    #pragma unroll
    for (int mi = 0; mi < 4; mi++) {
      int mrow0 = m0 + wm * 64 + mi * 16 + quad * 4;
      int b = mrow0 >> 11, tok0 = mrow0 & (NSEQ - 1);
      #pragma unroll
      for (int ni = 0; ni < 4; ni++) {
        int n = n0 + wn * 64 + ni * 16 + ml;
        int h = n >> 6, d = n & 63;
        u16x4 pk;
        #pragma unroll
        for (int r = 0; r < 4; r++) pk[r] = f2bf(acc[mi][ni][r]);
        *(u16x4*)&Vt[((size_t)(b * NH + h) * DH + d) * NSEQ + tok0] = pk;
      }
    }
  }
}

// ---------------------------------------------------------------------------
// Output projection: out = vhat[4096][1024] @ Wo + bo, fp32 out.
// grid (8, 32), 256 thr.
// ---------------------------------------------------------------------------
__global__ __launch_bounds__(256) void gemm_proj128(
    const u16* __restrict__ A, const u16* __restrict__ BtW,
    const float* __restrict__ bias, float* __restrict__ out) {
  GEMM128_MAINLOOP(A, BtW)
  #pragma unroll
  for (int ni = 0; ni < 4; ni++) {
    int n = n0 + wn * 64 + ni * 16 + ml;
    float bz = bias[n];
    #pragma unroll
    for (int mi = 0; mi < 4; mi++) {
      int mrow0 = m0 + wm * 64 + mi * 16 + quad * 4;
      #pragma unroll
      for (int r = 0; r < 4; r++)
        out[(size_t)(mrow0 + r) * DM + n] = acc[mi][ni][r] + bz;
    }
  }
}

// ---------------------------------------------------------------------------
// Barrier-free-mainloop MFMA flash attention, causal, NO online max
// (|score| small by L2 norm -> fixed softmax max=0; O and l additive).
// Block = 128 thr = 2 waves sharing 32 q-rows; wave p handles key tiles
// t === p (mod 2) -> per-tile work done by exactly one wave (L2 traffic
// unchanged) while resident waves double vs 1-wave blocks. K[key][d] and
// Vt[d][key] give 16B-contiguous B-frags read DIRECTLY from global
// (L2-resident, XCD-pinned via bh = blockIdx.x). NO __syncthreads in the
// K-loop; K-frags pipelined across steps via WAR ordering. One barrier at
// the end combines the two additive partials through LDS.
// exp2 path: Q pre-scaled by 0.125*log2(e) -> p = exp2(s) = one v_exp_f32.
// Heavy q-blocks dispatch first: qblk = 63 - blockIdx.y. grid (32,64),128 thr.
// ---------------------------------------------------------------------------
__global__ __launch_bounds__(128) void flash_attn(
    const u16* __restrict__ Qb, const u16* __restrict__ Kb,
    const u16* __restrict__ Vt, u16* __restrict__ vhat) {
  const int tid = threadIdx.x, w = tid >> 6, lane = tid & 63;
  const int ml = lane & 15, quad = lane >> 4;
  const int bh = blockIdx.x;                  // 0..31 (= b*NH + h)
  const int bb = bh >> 4, hb = bh & 15;
  const int qblk = 63 - (int)blockIdx.y;      // heavy blocks first
  const int q0 = qblk * 32;
  const u16* Qh = Qb + (size_t)bh * NSEQ * DH;
  const u16* Kh = Kb + (size_t)bh * NSEQ * DH;
  const u16* Vth = Vt + (size_t)bh * DH * NSEQ;

  __shared__ u16 Ps[2][32][40];     // per-wave P (C->A transform), 80B rows
  __shared__ float Ob[2][4][64][4]; // wave1 partial O, [m][n][lane][e]
  __shared__ float Lb[2][64][4];    // wave1 partial l, [m][lane][r]

  // Q A-frags: A[m=ml][k=quad*8+j]; m-tiles x k-chunks (same for both waves)
  short8 aq[2][2];
  #pragma unroll
  for (int m = 0; m < 2; m++)
    #pragma unroll
    for (int c = 0; c < 2; c++)
      aq[m][c] = *(const short8*)
          &Qh[(size_t)(q0 + m * 16 + ml) * DH + c * 32 + quad * 8];

  f32x4 oacc[2][4];
  #pragma unroll
  for (int m = 0; m < 2; m++)
    #pragma unroll
    for (int n = 0; n < 4; n++)
      #pragma unroll
      for (int e = 0; e < 4; e++) oacc[m][n][e] = 0.f;
  float l_[2][4] = {{0.f, 0.f, 0.f, 0.f}, {0.f, 0.f, 0.f, 0.f}};

  // preload K frags for this wave's first tile (t = w):
  // B-frag = K[key=n*16+ml][d=c*32+quad*8+j]
  short8 kf[2][2];
  #pragma unroll
  for (int n = 0; n < 2; n++)
    #pragma unroll
    for (int c = 0; c < 2; c++)
      kf[n][c] = *(const short8*)
          &Kh[(size_t)(w * 32 + n * 16 + ml) * DH + c * 32 + quad * 8];

  for (int t = w; t <= qblk; t += 2) {
    const int j0 = t * 32;
    // V frags for THIS tile (latency covered by S-MFMAs + exp):
    // B-frag = V^T[d=n*16+ml][key=quad*8+j]
    short8 vf[4];
    #pragma unroll
    for (int n = 0; n < 4; n++)
      vf[n] = *(const short8*)&Vth[(size_t)(n * 16 + ml) * NSEQ + j0 + quad * 8];

    // S = Q·K^T (32q x 32k) using kf loaded last iteration
    f32x4 sacc[2][2];
    #pragma unroll
    for (int m = 0; m < 2; m++)
      #pragma unroll
      for (int n = 0; n < 2; n++) {
        #pragma unroll
        for (int e = 0; e < 4; e++) sacc[m][n][e] = 0.f;
        #pragma unroll
        for (int c = 0; c < 2; c++)
          sacc[m][n] = __builtin_amdgcn_mfma_f32_16x16x32_bf16(
              aq[m][c], kf[n][c], sacc[m][n], 0, 0, 0);
      }

    // issue K loads for NEXT own tile (WAR on kf: issues after S consumes)
    const int j0n = (t + 2 <= qblk) ? (t + 2) * 32 : j0;
    #pragma unroll
    for (int n = 0; n < 2; n++)
      #pragma unroll
      for (int c = 0; c < 2; c++)
        kf[n][c] = *(const short8*)
            &Kh[(size_t)(j0n + n * 16 + ml) * DH + c * 32 + quad * 8];

    // p = exp2(s) (Q carries log2e), causal mask on diagonal tile only.
    // C-layout: col=ml(key), row=quad*4+r(q).
    const bool lastt = (t == qblk);
    #pragma unroll
    for (int m = 0; m < 2; m++)
      #pragma unroll
      for (int n = 0; n < 2; n++) {
        int j = j0 + n * 16 + ml;
        #pragma unroll
        for (int r = 0; r < 4; r++) {
          int q = q0 + m * 16 + quad * 4 + r;
          float e = __builtin_amdgcn_exp2f(sacc[m][n][r]);
          e = (lastt && j > q) ? 0.f : e;
          l_[m][r] += e;
          Ps[w][m * 16 + quad * 4 + r][n * 16 + ml] = f2bf(e);
        }
      }

    // O += P·V : A-frag = Ps[q=m*16+ml][key=quad*8+j] (same-wave lgkmcnt
    // ordering, no barrier)
    #pragma unroll
    for (int m = 0; m < 2; m++) {
      short8 ap = *(const short8*)&Ps[w][m * 16 + ml][quad * 8];
      #pragma unroll
      for (int n = 0; n < 4; n++)
        oacc[m][n] = __builtin_amdgcn_mfma_f32_16x16x32_bf16(
            ap, vf[n], oacc[m][n], 0, 0, 0);
    }
  }

  // combine the two waves' additive partials (single block barrier)
  if (w == 1) {
    #pragma unroll
    for (int m = 0; m < 2; m++) {
      #pragma unroll
      for (int n = 0; n < 4; n++)
        *(f32x4*)&Ob[m][n][lane][0] = oacc[m][n];
      f32x4 lv = {l_[m][0], l_[m][1], l_[m][2], l_[m][3]};
      *(f32x4*)&Lb[m][lane][0] = lv;
    }
  }
  __syncthreads();
  if (w == 0) {
    #pragma unroll
    for (int m = 0; m < 2; m++) {
      f32x4 lv = *(const f32x4*)&Lb[m][lane][0];
      #pragma unroll
      for (int r = 0; r < 4; r++) l_[m][r] += lv[r];
      #pragma unroll
      for (int n = 0; n < 4; n++) {
        f32x4 o2 = *(const f32x4*)&Ob[m][n][lane][0];
        #pragma unroll
        for (int e = 0; e < 4; e++) oacc[m][n][e] += o2[e];
      }
    }
    // reduce l over the 16 ml lanes of each quad group, write vhat
    #pragma unroll
    for (int m = 0; m < 2; m++)
      #pragma unroll
      for (int r = 0; r < 4; r++) {
        float lv = l_[m][r];
        lv += __shfl_xor(lv, 1, 64);
        lv += __shfl_xor(lv, 2, 64);
        lv += __shfl_xor(lv, 4, 64);
        lv += __shfl_xor(lv, 8, 64);
        float inv = 1.f / lv;
        int q = q0 + m * 16 + quad * 4 + r;
        #pragma unroll
        for (int n = 0; n < 4; n++)
          vhat[((size_t)(bb * NSEQ + q)) * DM + hb * DH + n * 16 + ml] =
              f2bf(oacc[m][n][r] * inv);
      }
  }
}

// ---------------------------------------------------------------------------
extern "C" void kernel_launch(void* const* d_in, const int* in_sizes, int n_in,
                              void* d_out, int out_size, void* d_ws, size_t ws_size,
                              hipStream_t stream) {
  const float* X  = (const float*)d_in[0];
  const float* Wq = (const float*)d_in[1];
  const float* Wk = (const float*)d_in[2];
  const float* Wv = (const float*)d_in[3];
  const float* Wo = (const float*)d_in[4];
  const float* bo = (const float*)d_in[5];
  float* out = (float*)d_out;

  // ws (all bf16, 8 MB each): Qb | Kb | Vt[B,H,DH,N] | {Xb then vhat, aliased}
  // | WT (4 transposed weights, 8 MB total) = 40 MB
  const size_t NE = (size_t)BATCH * NSEQ * DM;   // 4,194,304
  u16* Qb   = (u16*)d_ws;
  u16* Kb   = Qb + NE;
  u16* Vt   = Kb + NE;
  u16* XbVh = Vt + NE;                           // Xb / vhat (disjoint lifetimes)
  u16* WT   = XbVh + NE;

  prep        <<<dim3(3072),      256, 0, stream>>>(X, Wq, Wk, Wv, Wo, XbVh, WT);
  gemm_qkv128 <<<dim3(8, 32, 3),  256, 0, stream>>>(XbVh, WT, Qb, Kb, Vt);
  flash_attn  <<<dim3(32, 64),    128, 0, stream>>>(Qb, Kb, Vt, XbVh);
  gemm_proj128<<<dim3(8, 32, 1),  256, 0, stream>>>(XbVh, WT + 3 * (size_t)DM * DM,
                                                    bo, out);
}

// Round 10
// 214.818 us; speedup vs baseline: 1.0442x; 1.0437x over previous
//
#include <hip/hip_runtime.h>
#include <hip/hip_bf16.h>
#include <math.h>

// Problem: B=2, N=2048, D_MODEL=1024, H=16, D_HEAD=64. fp32 in/out,
// bf16 MFMA internal (threshold is bf16-grade: 2% of max|ref|).
#define BATCH 2
#define NSEQ  2048
#define DM    1024
#define NH    16
#define DH    64
#define EPS_N 1e-6f

typedef unsigned short u16;
typedef __attribute__((ext_vector_type(8))) short short8;       // bf16x8 MFMA frag
typedef __attribute__((ext_vector_type(8))) unsigned short u16x8;
typedef __attribute__((ext_vector_type(4))) unsigned short u16x4;
typedef __attribute__((ext_vector_type(4))) float f32x4;

__device__ __forceinline__ u16 f2bf(float x) {
  __hip_bfloat16 h = __float2bfloat16(x);          // round-to-nearest-even
  return *reinterpret_cast<u16*>(&h);
}

// async 16B global->LDS (lane i lands at lds_base + 16*i; src per-lane)
__device__ __forceinline__ void gl_lds16(const u16* g, u16* lds_base) {
  __builtin_amdgcn_global_load_lds(
      (__attribute__((address_space(1))) void*)g,
      (__attribute__((address_space(3))) void*)lds_base, 16, 0, 0);
}

// ---------------------------------------------------------------------------
// Prep: blocks 0..1023 transpose+cast the 4 weight matrices (out[n][k] =
// bf16(in[k][n])); blocks 1024..3071 cast X fp32->bf16. grid 3072, 256 thr.
// ---------------------------------------------------------------------------
__global__ __launch_bounds__(256) void prep(
    const float* __restrict__ X,
    const float* __restrict__ w0, const float* __restrict__ w1,
    const float* __restrict__ w2, const float* __restrict__ w3,
    u16* __restrict__ Xb, u16* __restrict__ WT) {
  const int id = blockIdx.x, tid = threadIdx.x;
  if (id >= 1024) {                       // ---- cast X chunk
    size_t base = ((size_t)(id - 1024) * 256 + tid) * 8;
    float4 f0 = *(const float4*)&X[base];
    float4 f1 = *(const float4*)&X[base + 4];
    u16x8 v;
    v[0] = f2bf(f0.x); v[1] = f2bf(f0.y); v[2] = f2bf(f0.z); v[3] = f2bf(f0.w);
    v[4] = f2bf(f1.x); v[5] = f2bf(f1.y); v[6] = f2bf(f1.z); v[7] = f2bf(f1.w);
    *(u16x8*)&Xb[base] = v;
    return;
  }
  // ---- weight transpose tile
  const int z = id >> 8, xy = id & 255, bx = xy & 15, by = xy >> 4;
  const float* in = (z == 0) ? w0 : (z == 1) ? w1 : (z == 2) ? w2 : w3;
  u16* o = WT + (size_t)z * DM * DM;
  __shared__ u16 T[64][65];
  const int n0 = bx * 64, k0 = by * 64;
  #pragma unroll
  for (int i = 0; i < 4; i++) {
    int c = tid + 256 * i, row = c >> 4, col4 = c & 15;
    float4 f = *(const float4*)&in[(size_t)(k0 + row) * DM + n0 + col4 * 4];
    T[row][col4 * 4 + 0] = f2bf(f.x);
    T[row][col4 * 4 + 1] = f2bf(f.y);
    T[row][col4 * 4 + 2] = f2bf(f.z);
    T[row][col4 * 4 + 3] = f2bf(f.w);
  }
  __syncthreads();
  #pragma unroll
  for (int i = 0; i < 2; i++) {
    int c = tid + 256 * i, row = c >> 3, col8 = c & 7;
    u16x8 v;
    #pragma unroll
    for (int e = 0; e < 8; e++) v[e] = T[col8 * 8 + e][row];
    *(u16x8*)&o[(size_t)(n0 + row) * DM + k0 + col8 * 8] = v;
  }
}

// ===========================================================================
// m97-style 128x128 GEMM mainloop (BK=64, global_load_lds 16B, XOR-swizzled
// LDS chunks). A[m][k], Bt[n][k] both bf16. 256 thr, 4 waves in 2x2 (wm,wn).
// LDS: row r (128 B) holds global chunk g at position g^(r&7).
// ===========================================================================
#define GEMM128_MAINLOOP(Aptr, Btptr)                                          \
  __shared__ u16 As[128 * 64];                                                 \
  __shared__ u16 Bs[128 * 64];                                                 \
  const int tid = threadIdx.x, w = tid >> 6, lane = tid & 63;                  \
  const int ml = lane & 15, quad = lane >> 4;                                  \
  const int m0 = blockIdx.y * 128, n0 = blockIdx.x * 128;                      \
  const int wm = w & 1, wn = w >> 1;                                           \
  const int srow = lane >> 3;                 /* 0..7 within 8-row slab */     \
  const int scol = ((lane & 7) ^ srow) * 8;   /* swizzled global chunk */      \
  f32x4 acc[4][4];                                                             \
  _Pragma("unroll") for (int mi = 0; mi < 4; mi++)                             \
    _Pragma("unroll") for (int ni = 0; ni < 4; ni++)                           \
      _Pragma("unroll") for (int e = 0; e < 4; e++) acc[mi][ni][e] = 0.f;      \
  for (int k0 = 0; k0 < DM; k0 += 64) {                                        \
    __syncthreads();                                                           \
    _Pragma("unroll") for (int L = 0; L < 4; L++) {                            \
      int I = w * 4 + L;                                                       \
      gl_lds16(Aptr  + (size_t)(m0 + I * 8 + srow) * DM + k0 + scol,           \
               As + I * 512);                                                  \
      gl_lds16(Btptr + (size_t)(n0 + I * 8 + srow) * DM + k0 + scol,           \
               Bs + I * 512);                                                  \
    }                                                                          \
    __syncthreads();                                                           \
    _Pragma("unroll") for (int kk = 0; kk < 64; kk += 32) {                    \
      const int kc = kk >> 3;                 /* chunk base: 0 or 4 */         \
      short8 am[4], bn[4];                                                     \
      _Pragma("unroll") for (int i = 0; i < 4; i++) {                          \
        int ra = wm * 64 + i * 16 + ml;                                        \
        int rb = wn * 64 + i * 16 + ml;                                        \
        am[i] = *(const short8*)&As[ra * 64 + (((quad + kc) ^ (ra & 7)) * 8)]; \
        bn[i] = *(const short8*)&Bs[rb * 64 + (((quad + kc) ^ (rb & 7)) * 8)]; \
      }                                                                        \
      _Pragma("unroll") for (int mi = 0; mi < 4; mi++)                         \
        _Pragma("unroll") for (int ni = 0; ni < 4; ni++)                       \
          acc[mi][ni] = __builtin_amdgcn_mfma_f32_16x16x32_bf16(               \
              am[mi], bn[ni], acc[mi][ni], 0, 0, 0);                           \
    }                                                                          \
  }

// ---------------------------------------------------------------------------
// QKV GEMM + fused L2 norm: Xb[4096][1024] bf16 @ W. z selects Q/K/V.
// Q,K: per-(head,token) L2-normalized in-register; Q also gets
// 0.125*log2(e) folded in (softmax 1/sqrt(64) + exp->exp2 conversion).
// V -> transposed [B,H,DH,N] (packed 8B stores). grid (8, 32, 3), 256 thr.
// ---------------------------------------------------------------------------
__global__ __launch_bounds__(256) void gemm_qkv128(
    const u16* __restrict__ Xb, const u16* __restrict__ WT,
    u16* __restrict__ Qo, u16* __restrict__ Ko, u16* __restrict__ Vt) {
  const u16* Bt = WT + (size_t)blockIdx.z * DM * DM;
  GEMM128_MAINLOOP(Xb, Bt)
  const int z = blockIdx.z;
  if (z < 2) {
    u16* OutQK = (z == 0) ? Qo : Ko;
    const float qsc = (z == 0) ? 0.125f * 1.44269504f : 1.0f;
    const int h = (n0 >> 6) + wn;                   // head of this wave's cols
    #pragma unroll
    for (int mi = 0; mi < 4; mi++) {
      int mrow0 = m0 + wm * 64 + mi * 16 + quad * 4;
      int b = mrow0 >> 11, tok0 = mrow0 & (NSEQ - 1);
      #pragma unroll
      for (int r = 0; r < 4; r++) {
        float ss = 0.f;
        #pragma unroll
        for (int ni = 0; ni < 4; ni++) ss += acc[mi][ni][r] * acc[mi][ni][r];
        ss += __shfl_xor(ss, 1, 64);
        ss += __shfl_xor(ss, 2, 64);
        ss += __shfl_xor(ss, 4, 64);
        ss += __shfl_xor(ss, 8, 64);    // sum over the 16 ml lanes (full row)
        float sc = qsc / (sqrtf(ss) + EPS_N);
        #pragma unroll
        for (int ni = 0; ni < 4; ni++)
          OutQK[((size_t)(b * NH + h) * NSEQ + tok0 + r) * DH + ni * 16 + ml] =
              f2bf(acc[mi][ni][r] * sc);
      }
    }
  } else {
    #pragma unroll
    for (int mi = 0; mi < 4; mi++) {
      int mrow0 = m0 + wm * 64 + mi * 16 + quad * 4;
      int b = mrow0 >> 11, tok0 = mrow0 & (NSEQ - 1);
      #pragma unroll
      for (int ni = 0; ni < 4; ni++) {
        int n = n0 + wn * 64 + ni * 16 + ml;
        int h = n >> 6, d = n & 63;
        u16x4 pk;
        #pragma unroll
        for (int r = 0; r < 4; r++) pk[r] = f2bf(acc[mi][ni][r]);
        *(u16x4*)&Vt[((size_t)(b * NH + h) * DH + d) * NSEQ + tok0] = pk;
      }
    }
  }
}

// ---------------------------------------------------------------------------
// Output projection: out = vhat[4096][1024] @ Wo + bo, fp32 out.
// grid (8, 32), 256 thr.
// ---------------------------------------------------------------------------
__global__ __launch_bounds__(256) void gemm_proj128(
    const u16* __restrict__ A, const u16* __restrict__ BtW,
    const float* __restrict__ bias, float* __restrict__ out) {
  GEMM128_MAINLOOP(A, BtW)
  #pragma unroll
  for (int ni = 0; ni < 4; ni++) {
    int n = n0 + wn * 64 + ni * 16 + ml;
    float bz = bias[n];
    #pragma unroll
    for (int mi = 0; mi < 4; mi++) {
      int mrow0 = m0 + wm * 64 + mi * 16 + quad * 4;
      #pragma unroll
      for (int r = 0; r < 4; r++)
        out[(size_t)(mrow0 + r) * DM + n] = acc[mi][ni][r] + bz;
    }
  }
}

// ---------------------------------------------------------------------------
// MFMA flash attention v10: LDS-staged (round-6 lineage, measured best) with
// Br=128 q-rows/block (4x staging amortization), async gl_lds16 staging into
// XOR-swizzled unpadded LDS (GEMM128-proven pattern), no online max
// (|score| small by L2 norm -> fixed softmax max=0).
// Block = 4 waves; wave w owns q-rows q0+32w..+31 across ALL keys -> no
// inter-wave combine, no end barrier; l-reduce = 4 shfl over ml lanes.
// Per 64-key tile: 2 barriers, 16 gl_lds16 (4/wave), 32 MFMA/wave
// (128 MFMA per barrier-pair). Causal mask applied every tile (Br>64 makes
// two partial tiles; unconditional cndmask is cheapest-correct).
// Balance: block does qblk pair {15-y, y} -> exactly 34 tiles/block.
// Grid (32 bh, 8) = 256 blocks, 1/CU; XCD pinned via bh%8. 256 thr.
// ---------------------------------------------------------------------------
__global__ __launch_bounds__(256) void flash_attn(
    const u16* __restrict__ Qb, const u16* __restrict__ Kb,
    const u16* __restrict__ Vt, u16* __restrict__ vhat) {
  const int tid = threadIdx.x, w = tid >> 6, lane = tid & 63;
  const int ml = lane & 15, quad = lane >> 4;
  const int bh = blockIdx.x;                  // 0..31 (= b*NH + h)
  const int bb = bh >> 4, hb = bh & 15;
  const u16* Qh = Qb + (size_t)bh * NSEQ * DH;
  const u16* Kh = Kb + (size_t)bh * NSEQ * DH;
  const u16* Vth = Vt + (size_t)bh * DH * NSEQ;

  // unpadded 128B rows, XOR-swizzled: row r holds global chunk g at pos g^(r&7)
  __shared__ u16 Ks [64 * 64];     // K[key][d]
  __shared__ u16 VsT[64 * 64];     // V^T[d][key]
  __shared__ u16 Ps [4][32][76];   // per-wave P[q][key] (C->A transform)

  const int srow = lane >> 3;                 // 0..7 within 8-row slab
  const int scol = ((lane & 7) ^ srow) * 8;   // swizzled source chunk

  for (int ph = 0; ph < 2; ph++) {
    const int qblk = ph ? (int)blockIdx.y : (15 - (int)blockIdx.y);
    const int q0 = qblk * 128;
    const int ntiles = 2 * (qblk + 1);

    // Q A-frags: A[m=ml][k=quad*8+j]; wave w rows q0+32w+m*16+ml
    short8 aq[2][2];
    #pragma unroll
    for (int m = 0; m < 2; m++)
      #pragma unroll
      for (int c = 0; c < 2; c++)
        aq[m][c] = *(const short8*)
            &Qh[(size_t)(q0 + w * 32 + m * 16 + ml) * DH + c * 32 + quad * 8];

    f32x4 oacc[2][4];
    #pragma unroll
    for (int m = 0; m < 2; m++)
      #pragma unroll
      for (int n = 0; n < 4; n++)
        #pragma unroll
        for (int e = 0; e < 4; e++) oacc[m][n][e] = 0.f;
    float l_[2][4] = {{0.f, 0.f, 0.f, 0.f}, {0.f, 0.f, 0.f, 0.f}};

    for (int t = 0; t < ntiles; t++) {
      const int j0 = t * 64;
      __syncthreads();                 // all waves done reading prev tile
      #pragma unroll
      for (int i2 = 0; i2 < 2; i2++) { // stage K + V^T: 4 gl_lds16 per wave
        int i = w + 4 * i2;
        gl_lds16(Kh  + (size_t)(j0 + i * 8 + srow) * DH + scol, Ks  + i * 512);
        gl_lds16(Vth + (size_t)(i * 8 + srow) * NSEQ + j0 + scol, VsT + i * 512);
      }
      __syncthreads();                 // fills drained + visible

      // S = Q·K^T (32q x 64k): B-frag = K[key=n*16+ml][d=c*32+quad*8+j]
      f32x4 sacc[2][4];
      #pragma unroll
      for (int m = 0; m < 2; m++)
        #pragma unroll
        for (int n = 0; n < 4; n++)
          #pragma unroll
          for (int e = 0; e < 4; e++) sacc[m][n][e] = 0.f;
      #pragma unroll
      for (int c = 0; c < 2; c++)
        #pragma unroll
        for (int n = 0; n < 4; n++) {
          int rk = n * 16 + ml;
          short8 kf = *(const short8*)
              &Ks[rk * 64 + (((c * 4 + quad) ^ (rk & 7)) * 8)];
          #pragma unroll
          for (int m = 0; m < 2; m++)
            sacc[m][n] = __builtin_amdgcn_mfma_f32_16x16x32_bf16(
                aq[m][c], kf, sacc[m][n], 0, 0, 0);
        }

      // p = exp2(s) (Q carries log2e), causal mask every tile.
      // C-layout: col=ml(key), row=quad*4+r(q).
      #pragma unroll
      for (int m = 0; m < 2; m++)
        #pragma unroll
        for (int n = 0; n < 4; n++) {
          int j = j0 + n * 16 + ml;
          #pragma unroll
          for (int r = 0; r < 4; r++) {
            int q = q0 + w * 32 + m * 16 + quad * 4 + r;
            float e = __builtin_amdgcn_exp2f(sacc[m][n][r]);
            e = (j > q) ? 0.f : e;
            l_[m][r] += e;
            Ps[w][m * 16 + quad * 4 + r][n * 16 + ml] = f2bf(e);
          }
        }

      // O += P·V : A-frag = Ps[q=m*16+ml][key=c*32+quad*8+j],
      //            B-frag = V^T[d=n*16+ml][key] (swizzled read)
      #pragma unroll
      for (int c = 0; c < 2; c++) {
        short8 ap[2];
        #pragma unroll
        for (int m = 0; m < 2; m++)
          ap[m] = *(const short8*)&Ps[w][m * 16 + ml][c * 32 + quad * 8];
        #pragma unroll
        for (int n = 0; n < 4; n++) {
          int rv = n * 16 + ml;
          short8 bv = *(const short8*)
              &VsT[rv * 64 + (((c * 4 + quad) ^ (rv & 7)) * 8)];
          #pragma unroll
          for (int m = 0; m < 2; m++)
            oacc[m][n] = __builtin_amdgcn_mfma_f32_16x16x32_bf16(
                ap[m], bv, oacc[m][n], 0, 0, 0);
        }
      }
    }

    // epilogue (per-wave, no barrier): reduce l over the 16 ml lanes
    #pragma unroll
    for (int m = 0; m < 2; m++)
      #pragma unroll
      for (int r = 0; r < 4; r++) {
        float lv = l_[m][r];
        lv += __shfl_xor(lv, 1, 64);
        lv += __shfl_xor(lv, 2, 64);
        lv += __shfl_xor(lv, 4, 64);
        lv += __shfl_xor(lv, 8, 64);
        float inv = 1.f / lv;
        int q = q0 + w * 32 + m * 16 + quad * 4 + r;
        #pragma unroll
        for (int n = 0; n < 4; n++)
          vhat[((size_t)(bb * NSEQ + q)) * DM + hb * DH + n * 16 + ml] =
              f2bf(oacc[m][n][r] * inv);
      }
  }
}

// ---------------------------------------------------------------------------
extern "C" void kernel_launch(void* const* d_in, const int* in_sizes, int n_in,
                              void* d_out, int out_size, void* d_ws, size_t ws_size,
                              hipStream_t stream) {
  const float* X  = (const float*)d_in[0];
  const float* Wq = (const float*)d_in[1];
  const float* Wk = (const float*)d_in[2];
  const float* Wv = (const float*)d_in[3];
  const float* Wo = (const float*)d_in[4];
  const float* bo = (const float*)d_in[5];
  float* out = (float*)d_out;

  // ws (all bf16, 8 MB each): Qb | Kb | Vt[B,H,DH,N] | {Xb then vhat, aliased}
  // | WT (4 transposed weights, 8 MB total) = 40 MB
  const size_t NE = (size_t)BATCH * NSEQ * DM;   // 4,194,304
  u16* Qb   = (u16*)d_ws;
  u16* Kb   = Qb + NE;
  u16* Vt   = Kb + NE;
  u16* XbVh = Vt + NE;                           // Xb / vhat (disjoint lifetimes)
  u16* WT   = XbVh + NE;

  prep        <<<dim3(3072),      256, 0, stream>>>(X, Wq, Wk, Wv, Wo, XbVh, WT);
  gemm_qkv128 <<<dim3(8, 32, 3),  256, 0, stream>>>(XbVh, WT, Qb, Kb, Vt);
  flash_attn  <<<dim3(32, 8),     256, 0, stream>>>(Qb, Kb, Vt, XbVh);
  gemm_proj128<<<dim3(8, 32, 1),  256, 0, stream>>>(XbVh, WT + 3 * (size_t)DM * DM,
                                                    bo, out);
}

// Round 11
// 207.219 us; speedup vs baseline: 1.0825x; 1.0367x over previous
//
#include <hip/hip_runtime.h>
#include <hip/hip_bf16.h>
#include <math.h>

// Problem: B=2, N=2048, D_MODEL=1024, H=16, D_HEAD=64. fp32 in/out,
// bf16 MFMA internal (threshold is bf16-grade: 2% of max|ref|).
#define BATCH 2
#define NSEQ  2048
#define DM    1024
#define NH    16
#define DH    64
#define EPS_N 1e-6f

typedef unsigned short u16;
typedef __attribute__((ext_vector_type(8))) short short8;       // bf16x8 MFMA frag
typedef __attribute__((ext_vector_type(8))) unsigned short u16x8;
typedef __attribute__((ext_vector_type(4))) unsigned short u16x4;
typedef __attribute__((ext_vector_type(4))) float f32x4;

__device__ __forceinline__ u16 f2bf(float x) {
  __hip_bfloat16 h = __float2bfloat16(x);          // round-to-nearest-even
  return *reinterpret_cast<u16*>(&h);
}

// async 16B global->LDS (lane i lands at lds_base + 16*i; src per-lane)
__device__ __forceinline__ void gl_lds16(const u16* g, u16* lds_base) {
  __builtin_amdgcn_global_load_lds(
      (__attribute__((address_space(1))) void*)g,
      (__attribute__((address_space(3))) void*)lds_base, 16, 0, 0);
}

// ---------------------------------------------------------------------------
// Prep: blocks 0..1023 transpose+cast the 4 weight matrices (out[n][k] =
// bf16(in[k][n])); blocks 1024..3071 cast X fp32->bf16. grid 3072, 256 thr.
// ---------------------------------------------------------------------------
__global__ __launch_bounds__(256) void prep(
    const float* __restrict__ X,
    const float* __restrict__ w0, const float* __restrict__ w1,
    const float* __restrict__ w2, const float* __restrict__ w3,
    u16* __restrict__ Xb, u16* __restrict__ WT) {
  const int id = blockIdx.x, tid = threadIdx.x;
  if (id >= 1024) {                       // ---- cast X chunk
    size_t base = ((size_t)(id - 1024) * 256 + tid) * 8;
    float4 f0 = *(const float4*)&X[base];
    float4 f1 = *(const float4*)&X[base + 4];
    u16x8 v;
    v[0] = f2bf(f0.x); v[1] = f2bf(f0.y); v[2] = f2bf(f0.z); v[3] = f2bf(f0.w);
    v[4] = f2bf(f1.x); v[5] = f2bf(f1.y); v[6] = f2bf(f1.z); v[7] = f2bf(f1.w);
    *(u16x8*)&Xb[base] = v;
    return;
  }
  // ---- weight transpose tile
  const int z = id >> 8, xy = id & 255, bx = xy & 15, by = xy >> 4;
  const float* in = (z == 0) ? w0 : (z == 1) ? w1 : (z == 2) ? w2 : w3;
  u16* o = WT + (size_t)z * DM * DM;
  __shared__ u16 T[64][65];
  const int n0 = bx * 64, k0 = by * 64;
  #pragma unroll
  for (int i = 0; i < 4; i++) {
    int c = tid + 256 * i, row = c >> 4, col4 = c & 15;
    float4 f = *(const float4*)&in[(size_t)(k0 + row) * DM + n0 + col4 * 4];
    T[row][col4 * 4 + 0] = f2bf(f.x);
    T[row][col4 * 4 + 1] = f2bf(f.y);
    T[row][col4 * 4 + 2] = f2bf(f.z);
    T[row][col4 * 4 + 3] = f2bf(f.w);
  }
  __syncthreads();
  #pragma unroll
  for (int i = 0; i < 2; i++) {
    int c = tid + 256 * i, row = c >> 3, col8 = c & 7;
    u16x8 v;
    #pragma unroll
    for (int e = 0; e < 8; e++) v[e] = T[col8 * 8 + e][row];
    *(u16x8*)&o[(size_t)(n0 + row) * DM + k0 + col8 * 8] = v;
  }
}

// ===========================================================================
// m97-style 128x128 GEMM mainloop (BK=64, global_load_lds 16B, XOR-swizzled
// LDS chunks). A[m][k], Bt[n][k] both bf16. 256 thr, 4 waves in 2x2 (wm,wn).
// LDS: row r (128 B) holds global chunk g at position g^(r&7).
// ===========================================================================
#define GEMM128_MAINLOOP(Aptr, Btptr)                                          \
  __shared__ u16 As[128 * 64];                                                 \
  __shared__ u16 Bs[128 * 64];                                                 \
  const int tid = threadIdx.x, w = tid >> 6, lane = tid & 63;                  \
  const int ml = lane & 15, quad = lane >> 4;                                  \
  const int m0 = blockIdx.y * 128, n0 = blockIdx.x * 128;                      \
  const int wm = w & 1, wn = w >> 1;                                           \
  const int srow = lane >> 3;                 /* 0..7 within 8-row slab */     \
  const int scol = ((lane & 7) ^ srow) * 8;   /* swizzled global chunk */      \
  f32x4 acc[4][4];                                                             \
  _Pragma("unroll") for (int mi = 0; mi < 4; mi++)                             \
    _Pragma("unroll") for (int ni = 0; ni < 4; ni++)                           \
      _Pragma("unroll") for (int e = 0; e < 4; e++) acc[mi][ni][e] = 0.f;      \
  for (int k0 = 0; k0 < DM; k0 += 64) {                                        \
    __syncthreads();                                                           \
    _Pragma("unroll") for (int L = 0; L < 4; L++) {                            \
      int I = w * 4 + L;                                                       \
      gl_lds16(Aptr  + (size_t)(m0 + I * 8 + srow) * DM + k0 + scol,           \
               As + I * 512);                                                  \
      gl_lds16(Btptr + (size_t)(n0 + I * 8 + srow) * DM + k0 + scol,           \
               Bs + I * 512);                                                  \
    }                                                                          \
    __syncthreads();                                                           \
    _Pragma("unroll") for (int kk = 0; kk < 64; kk += 32) {                    \
      const int kc = kk >> 3;                 /* chunk base: 0 or 4 */         \
      short8 am[4], bn[4];                                                     \
      _Pragma("unroll") for (int i = 0; i < 4; i++) {                          \
        int ra = wm * 64 + i * 16 + ml;                                        \
        int rb = wn * 64 + i * 16 + ml;                                        \
        am[i] = *(const short8*)&As[ra * 64 + (((quad + kc) ^ (ra & 7)) * 8)]; \
        bn[i] = *(const short8*)&Bs[rb * 64 + (((quad + kc) ^ (rb & 7)) * 8)]; \
      }                                                                        \
      _Pragma("unroll") for (int mi = 0; mi < 4; mi++)                         \
        _Pragma("unroll") for (int ni = 0; ni < 4; ni++)                       \
          acc[mi][ni] = __builtin_amdgcn_mfma_f32_16x16x32_bf16(               \
              am[mi], bn[ni], acc[mi][ni], 0, 0, 0);                           \
    }                                                                          \
  }

// ---------------------------------------------------------------------------
// QKV GEMM + fused L2 norm: Xb[4096][1024] bf16 @ W. z selects Q/K/V.
// Q,K: per-(head,token) L2-normalized in-register; Q also gets
// 0.125*log2(e) folded in (softmax 1/sqrt(64) + exp->exp2 conversion).
// V -> transposed [B,H,DH,N] (packed 8B stores). grid (8, 32, 3), 256 thr.
// ---------------------------------------------------------------------------
__global__ __launch_bounds__(256) void gemm_qkv128(
    const u16* __restrict__ Xb, const u16* __restrict__ WT,
    u16* __restrict__ Qo, u16* __restrict__ Ko, u16* __restrict__ Vt) {
  const u16* Bt = WT + (size_t)blockIdx.z * DM * DM;
  GEMM128_MAINLOOP(Xb, Bt)
  const int z = blockIdx.z;
  if (z < 2) {
    u16* OutQK = (z == 0) ? Qo : Ko;
    const float qsc = (z == 0) ? 0.125f * 1.44269504f : 1.0f;
    const int h = (n0 >> 6) + wn;                   // head of this wave's cols
    #pragma unroll
    for (int mi = 0; mi < 4; mi++) {
      int mrow0 = m0 + wm * 64 + mi * 16 + quad * 4;
      int b = mrow0 >> 11, tok0 = mrow0 & (NSEQ - 1);
      #pragma unroll
      for (int r = 0; r < 4; r++) {
        float ss = 0.f;
        #pragma unroll
        for (int ni = 0; ni < 4; ni++) ss += acc[mi][ni][r] * acc[mi][ni][r];
        ss += __shfl_xor(ss, 1, 64);
        ss += __shfl_xor(ss, 2, 64);
        ss += __shfl_xor(ss, 4, 64);
        ss += __shfl_xor(ss, 8, 64);    // sum over the 16 ml lanes (full row)
        float sc = qsc / (sqrtf(ss) + EPS_N);
        #pragma unroll
        for (int ni = 0; ni < 4; ni++)
          OutQK[((size_t)(b * NH + h) * NSEQ + tok0 + r) * DH + ni * 16 + ml] =
              f2bf(acc[mi][ni][r] * sc);
      }
    }
  } else {
    #pragma unroll
    for (int mi = 0; mi < 4; mi++) {
      int mrow0 = m0 + wm * 64 + mi * 16 + quad * 4;
      int b = mrow0 >> 11, tok0 = mrow0 & (NSEQ - 1);
      #pragma unroll
      for (int ni = 0; ni < 4; ni++) {
        int n = n0 + wn * 64 + ni * 16 + ml;
        int h = n >> 6, d = n & 63;
        u16x4 pk;
        #pragma unroll
        for (int r = 0; r < 4; r++) pk[r] = f2bf(acc[mi][ni][r]);
        *(u16x4*)&Vt[((size_t)(b * NH + h) * DH + d) * NSEQ + tok0] = pk;
      }
    }
  }
}

// ---------------------------------------------------------------------------
// Output projection: out = vhat[4096][1024] @ Wo + bo, fp32 out.
// grid (8, 32), 256 thr.
// ---------------------------------------------------------------------------
__global__ __launch_bounds__(256) void gemm_proj128(
    const u16* __restrict__ A, const u16* __restrict__ BtW,
    const float* __restrict__ bias, float* __restrict__ out) {
  GEMM128_MAINLOOP(A, BtW)
  #pragma unroll
  for (int ni = 0; ni < 4; ni++) {
    int n = n0 + wn * 64 + ni * 16 + ml;
    float bz = bias[n];
    #pragma unroll
    for (int mi = 0; mi < 4; mi++) {
      int mrow0 = m0 + wm * 64 + mi * 16 + quad * 4;
      #pragma unroll
      for (int r = 0; r < 4; r++)
        out[(size_t)(mrow0 + r) * DM + n] = acc[mi][ni][r] + bz;
    }
  }
}

// ---------------------------------------------------------------------------
// MFMA flash attention v11: Br=128 LDS-staged (v10) + DOUBLE-BUFFERED K/V
// staging -> ONE barrier per 64-key tile; stage(t+1) issued at top of
// compute(t), drained a full compute later (~1500 cyc) -> staged-load
// latency off the critical path. Causal mask only on the last two tiles.
// l computed via MFMA-with-ones (P·1 row sums in C-layout, aligned with
// oacc rows) -> no per-element adds, no epilogue shuffle reduce.
// No online max (|score| small by L2 norm -> fixed softmax max=0).
// Block = 4 waves; wave w owns q-rows q0+32w..+31 across ALL keys.
// Balance: block does qblk pair {15-y, y} -> exactly 34 tiles.
// Grid (32 bh, 8) = 256 blocks; XCD pinned via bh%8. 256 thr.
// ---------------------------------------------------------------------------
__global__ __launch_bounds__(256) void flash_attn(
    const u16* __restrict__ Qb, const u16* __restrict__ Kb,
    const u16* __restrict__ Vt, u16* __restrict__ vhat) {
  const int tid = threadIdx.x, w = tid >> 6, lane = tid & 63;
  const int ml = lane & 15, quad = lane >> 4;
  const int bh = blockIdx.x;                  // 0..31 (= b*NH + h)
  const int bb = bh >> 4, hb = bh & 15;
  const u16* Qh = Qb + (size_t)bh * NSEQ * DH;
  const u16* Kh = Kb + (size_t)bh * NSEQ * DH;
  const u16* Vth = Vt + (size_t)bh * DH * NSEQ;

  // double-buffered, unpadded 128B rows, XOR-swizzled (row r: chunk g at g^(r&7))
  __shared__ u16 Ks [2][64 * 64];  // K[key][d]
  __shared__ u16 VsT[2][64 * 64];  // V^T[d][key]
  __shared__ u16 Ps [4][32][76];   // per-wave P[q][key] (C->A transform)

  const int srow = lane >> 3;                 // 0..7 within 8-row slab
  const int scol = ((lane & 7) ^ srow) * 8;   // swizzled source chunk

  short8 ones;                                 // bf16 1.0 broadcast frag
  #pragma unroll
  for (int e = 0; e < 8; e++) ones[e] = (short)0x3F80;

  for (int ph = 0; ph < 2; ph++) {
    const int qblk = ph ? (int)blockIdx.y : (15 - (int)blockIdx.y);
    const int q0 = qblk * 128;
    const int ntiles = 2 * (qblk + 1);

    // Q A-frags: A[m=ml][k=quad*8+j]; wave w rows q0+32w+m*16+ml
    short8 aq[2][2];
    #pragma unroll
    for (int m = 0; m < 2; m++)
      #pragma unroll
      for (int c = 0; c < 2; c++)
        aq[m][c] = *(const short8*)
            &Qh[(size_t)(q0 + w * 32 + m * 16 + ml) * DH + c * 32 + quad * 8];

    f32x4 oacc[2][4], lacc[2];
    #pragma unroll
    for (int m = 0; m < 2; m++) {
      #pragma unroll
      for (int n = 0; n < 4; n++)
        #pragma unroll
        for (int e = 0; e < 4; e++) oacc[m][n][e] = 0.f;
      #pragma unroll
      for (int e = 0; e < 4; e++) lacc[m][e] = 0.f;
    }

    __syncthreads();                 // prev phase's readers done with bufs
    #pragma unroll
    for (int i2 = 0; i2 < 2; i2++) { // prologue: stage tile 0 -> buf 0
      int i = w + 4 * i2;
      gl_lds16(Kh  + (size_t)(i * 8 + srow) * DH + scol, Ks[0]  + i * 512);
      gl_lds16(Vth + (size_t)(i * 8 + srow) * NSEQ + scol, VsT[0] + i * 512);
    }

    for (int t = 0; t < ntiles; t++) {
      __syncthreads();               // stage(t) drained; buf[(t+1)&1] free
      if (t + 1 < ntiles) {
        const int j1 = (t + 1) * 64;
        #pragma unroll
        for (int i2 = 0; i2 < 2; i2++) {
          int i = w + 4 * i2;
          gl_lds16(Kh  + (size_t)(j1 + i * 8 + srow) * DH + scol,
                   Ks[(t + 1) & 1] + i * 512);
          gl_lds16(Vth + (size_t)(i * 8 + srow) * NSEQ + j1 + scol,
                   VsT[(t + 1) & 1] + i * 512);
        }
      }
      const u16* KsC  = Ks[t & 1];
      const u16* VsTC = VsT[t & 1];
      const int j0 = t * 64;

      // S = Q·K^T (32q x 64k): B-frag = K[key=n*16+ml][d=c*32+quad*8+j]
      f32x4 sacc[2][4];
      #pragma unroll
      for (int m = 0; m < 2; m++)
        #pragma unroll
        for (int n = 0; n < 4; n++)
          #pragma unroll
          for (int e = 0; e < 4; e++) sacc[m][n][e] = 0.f;
      #pragma unroll
      for (int c = 0; c < 2; c++)
        #pragma unroll
        for (int n = 0; n < 4; n++) {
          int rk = n * 16 + ml;
          short8 kf = *(const short8*)
              &KsC[rk * 64 + (((c * 4 + quad) ^ (rk & 7)) * 8)];
          #pragma unroll
          for (int m = 0; m < 2; m++)
            sacc[m][n] = __builtin_amdgcn_mfma_f32_16x16x32_bf16(
                aq[m][c], kf, sacc[m][n], 0, 0, 0);
        }

      // p = exp2(s) (Q carries log2e); mask only the last two (diagonal) tiles
      if (t >= ntiles - 2) {
        #pragma unroll
        for (int m = 0; m < 2; m++)
          #pragma unroll
          for (int n = 0; n < 4; n++) {
            int j = j0 + n * 16 + ml;
            #pragma unroll
            for (int r = 0; r < 4; r++) {
              int q = q0 + w * 32 + m * 16 + quad * 4 + r;
              float e = __builtin_amdgcn_exp2f(sacc[m][n][r]);
              e = (j > q) ? 0.f : e;
              Ps[w][m * 16 + quad * 4 + r][n * 16 + ml] = f2bf(e);
            }
          }
      } else {
        #pragma unroll
        for (int m = 0; m < 2; m++)
          #pragma unroll
          for (int n = 0; n < 4; n++)
            #pragma unroll
            for (int r = 0; r < 4; r++)
              Ps[w][m * 16 + quad * 4 + r][n * 16 + ml] =
                  f2bf(__builtin_amdgcn_exp2f(sacc[m][n][r]));
      }

      // O += P·V ; l += P·1 (MFMA row sums, C-layout rows == oacc rows)
      #pragma unroll
      for (int c = 0; c < 2; c++) {
        short8 ap[2];
        #pragma unroll
        for (int m = 0; m < 2; m++)
          ap[m] = *(const short8*)&Ps[w][m * 16 + ml][c * 32 + quad * 8];
        #pragma unroll
        for (int m = 0; m < 2; m++)
          lacc[m] = __builtin_amdgcn_mfma_f32_16x16x32_bf16(
              ap[m], ones, lacc[m], 0, 0, 0);
        #pragma unroll
        for (int n = 0; n < 4; n++) {
          int rv = n * 16 + ml;
          short8 bv = *(const short8*)
              &VsTC[rv * 64 + (((c * 4 + quad) ^ (rv & 7)) * 8)];
          #pragma unroll
          for (int m = 0; m < 2; m++)
            oacc[m][n] = __builtin_amdgcn_mfma_f32_16x16x32_bf16(
                ap[m], bv, oacc[m][n], 0, 0, 0);
        }
      }
    }

    // epilogue (per-wave, no barrier, no shuffle: lacc rows match oacc rows)
    #pragma unroll
    for (int m = 0; m < 2; m++)
      #pragma unroll
      for (int r = 0; r < 4; r++) {
        float inv = 1.f / lacc[m][r];
        int q = q0 + w * 32 + m * 16 + quad * 4 + r;
        #pragma unroll
        for (int n = 0; n < 4; n++)
          vhat[((size_t)(bb * NSEQ + q)) * DM + hb * DH + n * 16 + ml] =
              f2bf(oacc[m][n][r] * inv);
      }
  }
}

// ---------------------------------------------------------------------------
extern "C" void kernel_launch(void* const* d_in, const int* in_sizes, int n_in,
                              void* d_out, int out_size, void* d_ws, size_t ws_size,
                              hipStream_t stream) {
  const float* X  = (const float*)d_in[0];
  const float* Wq = (const float*)d_in[1];
  const float* Wk = (const float*)d_in[2];
  const float* Wv = (const float*)d_in[3];
  const float* Wo = (const float*)d_in[4];
  const float* bo = (const float*)d_in[5];
  float* out = (float*)d_out;

  // ws (all bf16, 8 MB each): Qb | Kb | Vt[B,H,DH,N] | {Xb then vhat, aliased}
  // | WT (4 transposed weights, 8 MB total) = 40 MB
  const size_t NE = (size_t)BATCH * NSEQ * DM;   // 4,194,304
  u16* Qb   = (u16*)d_ws;
  u16* Kb   = Qb + NE;
  u16* Vt   = Kb + NE;
  u16* XbVh = Vt + NE;                           // Xb / vhat (disjoint lifetimes)
  u16* WT   = XbVh + NE;

  prep        <<<dim3(3072),      256, 0, stream>>>(X, Wq, Wk, Wv, Wo, XbVh, WT);
  gemm_qkv128 <<<dim3(8, 32, 3),  256, 0, stream>>>(XbVh, WT, Qb, Kb, Vt);
  flash_attn  <<<dim3(32, 8),     256, 0, stream>>>(Qb, Kb, Vt, XbVh);
  gemm_proj128<<<dim3(8, 32, 1),  256, 0, stream>>>(XbVh, WT + 3 * (size_t)DM * DM,
                                                    bo, out);
}